// Round 4
// baseline (231.993 us; speedup 1.0000x reference)
//
#include <hip/hip_runtime.h>
#include <hip/hip_bf16.h>
#include <cmath>

typedef __bf16 bf16_t;
typedef __bf16 bf16x8 __attribute__((ext_vector_type(8)));
typedef float f32x4 __attribute__((ext_vector_type(4)));

#define MFMA16(A, B, C) __builtin_amdgcn_mfma_f32_16x16x32_bf16(A, B, C, 0, 0, 0)

// Async global->LDS DMA, 16 B per lane. LDS dest = wave-uniform base + lane*16.
#define GLOAD_LDS16(g, l)                                                      \
  __builtin_amdgcn_global_load_lds(                                            \
      (const __attribute__((address_space(1))) void*)(g),                      \
      (__attribute__((address_space(3))) void*)(l), 16, 0, 0)

#define BARRIER()                                                              \
  do {                                                                         \
    asm volatile("" ::: "memory");                                             \
    __builtin_amdgcn_s_barrier();                                              \
    asm volatile("" ::: "memory");                                             \
  } while (0)

// ---------------------------------------------------------------------------
// fp32 -> bf16 elementwise (x pre-convert), 8 elems/thread
// ---------------------------------------------------------------------------
__global__ __launch_bounds__(256) void f32_to_bf16(
    const float* __restrict__ src, bf16_t* __restrict__ dst) {
  const size_t i = (size_t)blockIdx.x * 256 + threadIdx.x;
  const float4 a0 = ((const float4*)src)[i * 2];
  const float4 a1 = ((const float4*)src)[i * 2 + 1];
  bf16x8 v = {(bf16_t)a0.x, (bf16_t)a0.y, (bf16_t)a0.z, (bf16_t)a0.w,
              (bf16_t)a1.x, (bf16_t)a1.y, (bf16_t)a1.z, (bf16_t)a1.w};
  ((bf16x8*)dst)[i] = v;
}

// ---------------------------------------------------------------------------
// Transpose fp32 src[R][C] -> bf16 dst[C][R]  (R, C multiples of 32)
// ---------------------------------------------------------------------------
__global__ __launch_bounds__(256) void transpose_f32_to_bf16(
    const float* __restrict__ src, bf16_t* __restrict__ dst, int R, int C) {
  __shared__ bf16_t tile[32][33];
  const int c0 = blockIdx.x * 32, r0 = blockIdx.y * 32;
  const int tr = threadIdx.x >> 5;   // 0..7
  const int tc = threadIdx.x & 31;   // 0..31
#pragma unroll
  for (int i = 0; i < 32; i += 8)
    tile[tr + i][tc] = (bf16_t)src[(size_t)(r0 + tr + i) * C + (c0 + tc)];
  __syncthreads();
#pragma unroll
  for (int i = 0; i < 32; i += 8)
    dst[(size_t)(c0 + tr + i) * R + (r0 + tc)] = tile[tc][tr + i];
}

// ---------------------------------------------------------------------------
// QKV GEMM, 8-phase counted-vmcnt schedule (T3+T4+T5 port of the 256^2
// template). BM=BN=256, BK=64 stored as two K=32 planes [buf][ks][256][32];
// 512 thr = 8 waves (2M x 4N, per-wave 128x64, acc[8][4]). LDS 128 KB.
// Per K-tile: 4 phases = (ks, m-half), 16 MFMA each, setprio(1) wrapped.
// Per phase stage ONE 16 KB unit (2 gloads/wave) of tile t+1 into buf^1:
//   ph1: A-ks0, ph2: B-ks0, ph3: A-ks1, ph4: B-ks1.
// s_waitcnt vmcnt(4) at even-phase ends (never 0 in steady state):
//   end-ph2 retires {A-ks1,B-ks1}(t)   -> needed by ph3 reads;
//   end-ph4 retires {A-ks0,B-ks0}(t+1) -> needed by next ph1 reads;
//   the 2 newest units keep 2-4 phases (~500-1000 cy) of latency cover.
// WAR safe: staging targets buf^1, last read before previous tile boundary.
// Row layout: 32 elems = 4 x 16B chunks, XOR swizzle slot=(chunk+((r>>1)&3))&3
// (round-0 verified family, 0 bank conflicts). Grid 288 = 32m x 9n, XCD
// decode (36/XCD). Scatter: q/k [B*H][T][64], vt [B*H][64][T].
// ---------------------------------------------------------------------------
__global__ __launch_bounds__(512, 2) void gemm_qkv(
    const bf16_t* __restrict__ A, const bf16_t* __restrict__ BT,
    const float* __restrict__ bias,
    bf16_t* __restrict__ o0, bf16_t* __restrict__ o1, bf16_t* __restrict__ o2,
    int K) {
  extern __shared__ __align__(16) bf16_t smem[];
  // A planes: smem + (p*2+ks)*8192 ; B planes: smem + 32768 + (p*2+ks)*8192
  auto Apl = [&](int p, int ks) { return smem + ((p * 2 + ks) << 13); };
  auto Bpl = [&](int p, int ks) { return smem + 32768 + ((p * 2 + ks) << 13); };

  const int tid = threadIdx.x;
  const int w = tid >> 6, lane = tid & 63;
  const int wr = w >> 2, wc = w & 3;          // 2M x 4N wave grid
  const int quad = lane >> 4, l16 = lane & 15;

  // XCD-aware decode: grid = 288 = 9 n-tiles x 32 m-tiles, 36 blocks/XCD.
  const int id = blockIdx.x;
  const int xcd = id & 7;
  const int lin = id >> 3;          // 0..35
  const int nt = lin % 9;           // n fastest
  const int mt = (xcd << 2) + lin / 9;

  // DMA mapping (verified round-0 family): lane -> row lane>>2 of 16-row
  // group, LDS slot lane&3; fetch global chunk ((lane&3)-((lane>>3)&3))&3.
  const int rl = lane >> 2;
  const int cq = ((lane & 3) - (rl >> 1)) & 3;
  // Swizzle-corrected fragment read offset (rows base+l16, base%16==0).
  const int sw = ((quad + (l16 >> 1)) & 3) << 3;

  f32x4 acc[8][4] = {};

  auto stageA = [&](int t, int s, int ks) {
    const bf16_t* g =
        A + (size_t)(mt * 256 + w * 32 + rl) * K + t * 64 + ks * 32 + cq * 8;
    bf16_t* l = Apl(s, ks) + (w * 32) * 32;
    GLOAD_LDS16(g, l);
    GLOAD_LDS16(g + (size_t)16 * K, l + 16 * 32);
  };
  auto stageB = [&](int t, int s, int ks) {
    const bf16_t* g =
        BT + (size_t)(nt * 256 + w * 32 + rl) * K + t * 64 + ks * 32 + cq * 8;
    bf16_t* l = Bpl(s, ks) + (w * 32) * 32;
    GLOAD_LDS16(g, l);
    GLOAD_LDS16(g + (size_t)16 * K, l + 16 * 32);
  };

  bf16x8 bfr[4], af[4];
  auto ldB = [&](int p, int ks) {
#pragma unroll
    for (int ni = 0; ni < 4; ++ni)
      bfr[ni] = *(const bf16x8*)(Bpl(p, ks) +
                                 (wc * 64 + ni * 16 + l16) * 32 + sw);
  };
  auto ldA = [&](int p, int ks, int mh) {
#pragma unroll
    for (int mi = 0; mi < 4; ++mi)
      af[mi] = *(const bf16x8*)(Apl(p, ks) +
                                (wr * 128 + mh * 64 + mi * 16 + l16) * 32 + sw);
  };
  auto mfma16 = [&](int mh) {
    __builtin_amdgcn_s_setprio(1);
#pragma unroll
    for (int mi = 0; mi < 4; ++mi)
#pragma unroll
      for (int ni = 0; ni < 4; ++ni)
        acc[mh * 4 + mi][ni] = MFMA16(af[mi], bfr[ni], acc[mh * 4 + mi][ni]);
    __builtin_amdgcn_s_setprio(0);
  };

  const int NIT = K / 64;  // 12
  // Prologue: tile 0 units in order {A0,B0,A1,B1}; wait for the ks0 pair.
  stageA(0, 0, 0);
  stageB(0, 0, 0);
  stageA(0, 0, 1);
  stageB(0, 0, 1);
  asm volatile("s_waitcnt vmcnt(4)" ::: "memory");
  BARRIER();

  for (int t = 0; t < NIT; ++t) {
    const int p = t & 1, nxt = p ^ 1;
    const bool pf = (t + 1 < NIT);
    // ---- ph1: ks0, m-half0
    ldB(p, 0);
    ldA(p, 0, 0);
    if (pf) stageA(t + 1, nxt, 0);
    BARRIER();
    mfma16(0);
    BARRIER();
    // ---- ph2: ks0, m-half1
    ldA(p, 0, 1);
    if (pf) stageB(t + 1, nxt, 0);
    BARRIER();
    mfma16(1);
    if (pf)
      asm volatile("s_waitcnt vmcnt(4)" ::: "memory");
    else
      asm volatile("s_waitcnt vmcnt(0)" ::: "memory");
    BARRIER();
    // ---- ph3: ks1, m-half0
    ldB(p, 1);
    ldA(p, 1, 0);
    if (pf) stageA(t + 1, nxt, 1);
    BARRIER();
    mfma16(0);
    BARRIER();
    // ---- ph4: ks1, m-half1
    ldA(p, 1, 1);
    if (pf) stageB(t + 1, nxt, 1);
    BARRIER();
    mfma16(1);
    if (pf) asm volatile("s_waitcnt vmcnt(4)" ::: "memory");
    BARRIER();
  }

  // Epilogue. C/D layout: col = l16 (n), row = quad*4 + r (m).
  const int m_base = mt * 256 + wr * 128;
  const int n_base = nt * 256 + wc * 64;
#pragma unroll
  for (int ni = 0; ni < 4; ++ni) {
    const int n = n_base + ni * 16 + l16;
    const float bv = bias[n];
    const int which = n / 768;
    const int c = n - which * 768;
    const int h = c >> 6, d = c & 63;
#pragma unroll
    for (int mi = 0; mi < 8; ++mi) {
#pragma unroll
      for (int r = 0; r < 4; ++r) {
        const int m = m_base + mi * 16 + quad * 4 + r;
        const bf16_t bw = (bf16_t)(acc[mi][ni][r] + bv);
        const int b = m >> 10, t = m & 1023;
        const size_t bh = (size_t)(b * 12 + h);
        if (which == 0)
          o0[(bh * 1024 + t) * 64 + d] = bw;
        else if (which == 1)
          o1[(bh * 1024 + t) * 64 + d] = bw;
        else
          o2[(bh * 64 + d) * 1024 + t] = bw;
      }
    }
  }
}

// ---------------------------------------------------------------------------
// Proj GEMM (verified structure): of[M][N] = A*BT^T + bias, fp32 out.
// XCD-aware decode. nwg=384 -> each XCD owns 8 m-tiles x all 6 n-tiles.
// ---------------------------------------------------------------------------
__global__ __launch_bounds__(256) void gemm_proj(
    const bf16_t* __restrict__ A, const bf16_t* __restrict__ BT,
    const float* __restrict__ bias, float* __restrict__ of, int N, int K) {
  constexpr int BM = 128, BN = 128, BK = 32;
  __shared__ __align__(16) bf16_t As[2][BM][BK];
  __shared__ __align__(16) bf16_t Bs[2][BN][BK];

  const int tid = threadIdx.x;
  const int wave = tid >> 6, lane = tid & 63;
  const int wr = wave >> 1, wc = wave & 1;
  const int quad = lane >> 4, l16 = lane & 15;

  // XCD-aware decode: grid = 384 = 6 n-tiles x 64 m-tiles.
  const int id = blockIdx.x;
  const int xcd = id & 7;
  const int lin = id >> 3;     // 0..47
  const int nt = lin % 6;
  const int mt = xcd * 8 + lin / 6;

  const int rl = lane >> 2;
  const int cq = ((lane & 3) - (rl >> 1)) & 3;
  const int ac = cq << 3;
  const bf16_t* Ag0 = A + (size_t)(mt * BM + wave * 32 + rl) * K + ac;
  const bf16_t* Ag1 = Ag0 + (size_t)16 * K;
  const bf16_t* Bg0 = BT + (size_t)(nt * BN + wave * 32 + rl) * K + ac;
  const bf16_t* Bg1 = Bg0 + (size_t)16 * K;

  const int sw = ((quad + (l16 >> 1)) & 3) << 3;

  f32x4 acc[4][4] = {};

  auto stage = [&](int k0, int buf) {
    GLOAD_LDS16(Ag0 + k0, &As[buf][wave * 32][0]);
    GLOAD_LDS16(Ag1 + k0, &As[buf][wave * 32 + 16][0]);
    GLOAD_LDS16(Bg0 + k0, &Bs[buf][wave * 32][0]);
    GLOAD_LDS16(Bg1 + k0, &Bs[buf][wave * 32 + 16][0]);
  };
  auto compute = [&](int buf) {
    bf16x8 af[4], bfr[4];
#pragma unroll
    for (int mi = 0; mi < 4; ++mi)
      af[mi] = *(const bf16x8*)(&As[buf][wr * 64 + mi * 16 + l16][sw]);
#pragma unroll
    for (int ni = 0; ni < 4; ++ni)
      bfr[ni] = *(const bf16x8*)(&Bs[buf][wc * 64 + ni * 16 + l16][sw]);
#pragma unroll
    for (int mi = 0; mi < 4; ++mi)
#pragma unroll
      for (int ni = 0; ni < 4; ++ni)
        acc[mi][ni] = MFMA16(af[mi], bfr[ni], acc[mi][ni]);
  };

  const int NIT = K / BK;  // 24
  stage(0, 0);
  for (int k = 0; k + 2 < NIT; k += 2) {
    __syncthreads();
    stage((k + 1) * BK, 1);
    compute(0);
    __syncthreads();
    stage((k + 2) * BK, 0);
    compute(1);
  }
  __syncthreads();
  stage((NIT - 1) * BK, 1);
  compute(0);
  __syncthreads();
  compute(1);

  const int m_base = mt * BM + wr * 64;
  const int n_base = nt * BN + wc * 64;
#pragma unroll
  for (int ni = 0; ni < 4; ++ni) {
    const int n = n_base + ni * 16 + l16;
    const float bv = bias[n];
#pragma unroll
    for (int mi = 0; mi < 4; ++mi)
#pragma unroll
      for (int r = 0; r < 4; ++r) {
        const int m = m_base + mi * 16 + quad * 4 + r;
        of[(size_t)m * N + n] = acc[mi][ni][r] + bv;
      }
  }
}

// ---------------------------------------------------------------------------
// Causal flash attention, DMA-staged K/V, double-buffered, ONE barrier/tile.
// Q,K: [B*H][1024][64]; VT: [B*H][64][1024]; Y: [B][1024][768].
// XCD-aware decode: each XCD owns one batch b; the 8 pair-blocks sharing a
// head's K/V are co-located on one XCD's L2.
// ---------------------------------------------------------------------------
__global__ __launch_bounds__(256) void attn_fwd(
    const bf16_t* __restrict__ Q, const bf16_t* __restrict__ Kg,
    const bf16_t* __restrict__ VT, bf16_t* __restrict__ Y) {
  __shared__ __align__(16) bf16_t Ks[2][64][64];  // 16 KB
  __shared__ __align__(16) bf16_t Vs[2][64][64];  // 16 KB  (row = d)
  __shared__ __align__(16) bf16_t Ps[4][16][72];  // 9 KB, padded (VALU-written)

  const int tid = threadIdx.x;
  const int w = tid >> 6, lane = tid & 63;
  const int quad = lane >> 4, l16 = lane & 15;

  // XCD-aware decode: grid = 768 = 8 pairs x 12 h x 8 b.
  const int id = blockIdx.x;
  const int xcd = id & 7;
  const int lin = id >> 3;          // 0..95
  const int pair = lin & 7;
  const int h = lin >> 3;           // 0..11
  const int b = xcd;                // each XCD owns one batch
  const size_t bh = (size_t)(b * 12 + h);
  const bf16_t* Qbh = Q + bh * 65536;
  const bf16_t* Kbh = Kg + bh * 65536;
  const bf16_t* VTbh = VT + bh * 65536;

  // DMA fetch mapping: lane -> row lane>>3 (of an 8-row group), slot lane&7,
  // fetches global chunk (slot - row)&7 so that slot = (chunk + row)&7.
  const int drow = lane >> 3;
  const int dchunk = (((lane & 7) - drow) & 7) << 3;  // element offset

  // swizzle-corrected fragment read offsets (rows base+l16, base%16==0)
  const int so0 = ((quad + (l16 & 7)) & 7) << 3;
  const int so1 = so0 ^ 32;

  constexpr float SC = 0.18033688011112042f;  // log2(e) / sqrt(64)
  const bf16_t one_b = (bf16_t)1.0f;
  const bf16x8 ones = {one_b, one_b, one_b, one_b,
                       one_b, one_b, one_b, one_b};

  auto stageKV = [&](int kt, int bufi) {
#pragma unroll
    for (int j = 0; j < 2; ++j) {
      const int r = w * 16 + j * 8 + drow;
      GLOAD_LDS16(Kbh + (size_t)(kt * 64 + r) * 64 + dchunk,
                  &Ks[bufi][w * 16 + j * 8][0]);
      GLOAD_LDS16(VTbh + (size_t)r * 1024 + kt * 64 + dchunk,
                  &Vs[bufi][w * 16 + j * 8][0]);
    }
  };

  for (int phase = 0; phase < 2; ++phase) {
    const int qt = phase ? pair : (15 - pair);  // big tile first

    const int qrow = qt * 64 + w * 16 + l16;
    bf16x8 qf0 = *(const bf16x8*)(Qbh + (size_t)qrow * 64 + quad * 8);
    bf16x8 qf1 = *(const bf16x8*)(Qbh + (size_t)qrow * 64 + 32 + quad * 8);

    float m_r[4];
    f32x4 o[5] = {};  // o[0..3]: V columns; o[4]: row-sum (l)
#pragma unroll
    for (int r = 0; r < 4; ++r) m_r[r] = -INFINITY;

    __syncthreads();  // all waves done reading prev-phase LDS
    stageKV(0, 0);
    int buf = 0;
    for (int kt = 0; kt <= qt; ++kt) {
      __syncthreads();  // DMA(kt) landed; prior reads of buf^1 done
      if (kt < qt) stageKV(kt + 1, buf ^ 1);

      // S = Q * K^T
      f32x4 s[4];
#pragma unroll
      for (int ni = 0; ni < 4; ++ni) {
        bf16x8 kf0 = *(const bf16x8*)(&Ks[buf][ni * 16 + l16][so0]);
        bf16x8 kf1 = *(const bf16x8*)(&Ks[buf][ni * 16 + l16][so1]);
        f32x4 t = {};
        t = MFMA16(qf0, kf0, t);
        t = MFMA16(qf1, kf1, t);
        s[ni] = t;
      }
      if (kt == qt) {
#pragma unroll
        for (int ni = 0; ni < 4; ++ni)
#pragma unroll
          for (int r = 0; r < 4; ++r) {
            const int kp = ni * 16 + l16;
            const int qr = w * 16 + quad * 4 + r;
            s[ni][r] = (kp > qr) ? -INFINITY : s[ni][r] * SC;
          }
      } else {
#pragma unroll
        for (int ni = 0; ni < 4; ++ni)
#pragma unroll
          for (int r = 0; r < 4; ++r) s[ni][r] *= SC;
      }
      float alpha[4];
#pragma unroll
      for (int r = 0; r < 4; ++r) {
        float v = fmaxf(fmaxf(s[0][r], s[1][r]), fmaxf(s[2][r], s[3][r]));
        v = fmaxf(v, __shfl_xor(v, 1));
        v = fmaxf(v, __shfl_xor(v, 2));
        v = fmaxf(v, __shfl_xor(v, 4));
        v = fmaxf(v, __shfl_xor(v, 8));
        const float mn = fmaxf(m_r[r], v);
        alpha[r] = exp2f(m_r[r] - mn);
        m_r[r] = mn;
      }
      // P -> Ps (per-wave region; intra-wave dependency only, no barrier)
#pragma unroll
      for (int ni = 0; ni < 4; ++ni)
#pragma unroll
        for (int r = 0; r < 4; ++r)
          Ps[w][quad * 4 + r][ni * 16 + l16] =
              (bf16_t)exp2f(s[ni][r] - m_r[r]);
#pragma unroll
      for (int nd = 0; nd < 5; ++nd)
#pragma unroll
        for (int r = 0; r < 4; ++r) o[nd][r] *= alpha[r];

      bf16x8 pf0 = *(const bf16x8*)(&Ps[w][l16][quad * 8]);
      bf16x8 pf1 = *(const bf16x8*)(&Ps[w][l16][32 + quad * 8]);
#pragma unroll
      for (int nd = 0; nd < 4; ++nd) {
        bf16x8 vf0 = *(const bf16x8*)(&Vs[buf][nd * 16 + l16][so0]);
        bf16x8 vf1 = *(const bf16x8*)(&Vs[buf][nd * 16 + l16][so1]);
        o[nd] = MFMA16(pf0, vf0, o[nd]);
        o[nd] = MFMA16(pf1, vf1, o[nd]);
      }
      o[4] = MFMA16(pf0, ones, o[4]);
      o[4] = MFMA16(pf1, ones, o[4]);
      buf ^= 1;
    }

#pragma unroll
    for (int r = 0; r < 4; ++r) {
      const float inv = 1.0f / o[4][r];
      const int t = qt * 64 + w * 16 + quad * 4 + r;
      bf16_t* yrow = Y + ((size_t)b * 1024 + t) * 768 + h * 64;
#pragma unroll
      for (int nd = 0; nd < 4; ++nd)
        yrow[nd * 16 + l16] = (bf16_t)(o[nd][r] * inv);
    }
  }
}

// ---------------------------------------------------------------------------
extern "C" void kernel_launch(void* const* d_in, const int* in_sizes, int n_in,
                              void* d_out, int out_size, void* d_ws,
                              size_t ws_size, hipStream_t stream) {
  const float* x      = (const float*)d_in[0];
  const float* W_attn = (const float*)d_in[1];
  const float* b_attn = (const float*)d_in[2];
  const float* W_proj = (const float*)d_in[3];
  const float* b_proj = (const float*)d_in[4];
  float* out = (float*)d_out;   // fp32 output per reference dtype

  const size_t HEADS = 96;  // B*H = 8*12
  bf16_t* wta = (bf16_t*)d_ws;                  // [2304][768]
  bf16_t* wtp = wta + (size_t)2304 * 768;       // [768][768]
  bf16_t* qw  = wtp + (size_t)768 * 768;        // [96][1024][64]
  bf16_t* kw  = qw + HEADS * 1024 * 64;         // [96][1024][64]
  bf16_t* vtw = kw + HEADS * 1024 * 64;         // [96][64][1024]
  bf16_t* yw  = vtw + HEADS * 1024 * 64;        // [8192][768]
  bf16_t* xb  = yw + (size_t)8192 * 768;        // [8192][768] bf16 x

  f32_to_bf16<<<dim3(8192 * 768 / (256 * 8)), 256, 0, stream>>>(x, xb);
  transpose_f32_to_bf16<<<dim3(2304 / 32, 768 / 32), 256, 0, stream>>>(
      W_attn, wta, 768, 2304);
  transpose_f32_to_bf16<<<dim3(768 / 32, 768 / 32), 256, 0, stream>>>(
      W_proj, wtp, 768, 768);
  // Dynamic LDS: 2 bufs x 2 ks-planes x (256x32 A + 256x32 B) bf16 = 128 KB.
  const size_t qkv_lds = (size_t)131072;
  gemm_qkv<<<dim3(288), 512, qkv_lds, stream>>>(
      xb, wta, b_attn, qw, kw, vtw, 768);
  attn_fwd<<<dim3(768), 256, 0, stream>>>(qw, kw, vtw, yw);
  gemm_proj<<<dim3(384), 256, 0, stream>>>(
      yw, wtp, b_proj, out, 768, 768);
}

// Round 5
// 211.575 us; speedup vs baseline: 1.0965x; 1.0965x over previous
//
#include <hip/hip_runtime.h>
#include <hip/hip_bf16.h>
#include <cmath>

typedef __bf16 bf16_t;
typedef __bf16 bf16x8 __attribute__((ext_vector_type(8)));
typedef float f32x4 __attribute__((ext_vector_type(4)));

#define MFMA16(A, B, C) __builtin_amdgcn_mfma_f32_16x16x32_bf16(A, B, C, 0, 0, 0)

// Async global->LDS DMA, 16 B per lane. LDS dest = wave-uniform base + lane*16.
#define GLOAD_LDS16(g, l)                                                      \
  __builtin_amdgcn_global_load_lds(                                            \
      (const __attribute__((address_space(1))) void*)(g),                      \
      (__attribute__((address_space(3))) void*)(l), 16, 0, 0)

// ---------------------------------------------------------------------------
// fp32 -> bf16 elementwise (x pre-convert), 8 elems/thread
// ---------------------------------------------------------------------------
__global__ __launch_bounds__(256) void f32_to_bf16(
    const float* __restrict__ src, bf16_t* __restrict__ dst) {
  const size_t i = (size_t)blockIdx.x * 256 + threadIdx.x;
  const float4 a0 = ((const float4*)src)[i * 2];
  const float4 a1 = ((const float4*)src)[i * 2 + 1];
  bf16x8 v = {(bf16_t)a0.x, (bf16_t)a0.y, (bf16_t)a0.z, (bf16_t)a0.w,
              (bf16_t)a1.x, (bf16_t)a1.y, (bf16_t)a1.z, (bf16_t)a1.w};
  ((bf16x8*)dst)[i] = v;
}

// ---------------------------------------------------------------------------
// Transpose fp32 src[R][C] -> bf16 dst[C][R]  (R, C multiples of 32)
// ---------------------------------------------------------------------------
__global__ __launch_bounds__(256) void transpose_f32_to_bf16(
    const float* __restrict__ src, bf16_t* __restrict__ dst, int R, int C) {
  __shared__ bf16_t tile[32][33];
  const int c0 = blockIdx.x * 32, r0 = blockIdx.y * 32;
  const int tr = threadIdx.x >> 5;   // 0..7
  const int tc = threadIdx.x & 31;   // 0..31
#pragma unroll
  for (int i = 0; i < 32; i += 8)
    tile[tr + i][tc] = (bf16_t)src[(size_t)(r0 + tr + i) * C + (c0 + tc)];
  __syncthreads();
#pragma unroll
  for (int i = 0; i < 32; i += 8)
    dst[(size_t)(c0 + tr + i) * R + (r0 + tc)] = tile[tc][tr + i];
}

// ---------------------------------------------------------------------------
// QKV GEMM, balanced grid: BM=256 x BN=288, BK=64, 768 threads = 12 waves
// (2M x 6N, per-wave 128x48 = round-3's verified per-wave shape, acc[8][3]).
// Grid = 32m x 8n = 256 blocks -> EXACTLY 1 block/CU, no makespan tail
// (round-3's 384-block grid at 1-resident serialized 2 blocks on half the
// CUs = 2x T_block). 3 waves/SIMD (vs 2) adds TLP to fill the 2-phase stall.
// Sync skeleton byte-identical to round-3: stage(t+1) -> compute(t) ->
// __syncthreads, double-buffered. LDS 136 KB dynamic.
// Rows = 64 elems = 8 x 16B chunks, XOR swizzle slot=(chunk+(row&7))&7
// (verified family, 0 bank conflicts): DMA lane fetches chunk
// ((lane&7)-(lane>>3))&7 of row lane>>3; frag read offset
// ((quad+(l16&7))&7)<<3, ks=1 => ^32. Staging: 68 8-row chunks (32 A + 36 B)
// striped over 12 waves (waves 0-7: 6 units, 8-11: 5).
// XCD decode: 32 blocks/XCD = 4m x 8n, n-fastest.
// Scatter: q/k [B*H][T][64], vt [B*H][64][T].
// ---------------------------------------------------------------------------
__global__ __launch_bounds__(768, 1) void gemm_qkv(
    const bf16_t* __restrict__ A, const bf16_t* __restrict__ BT,
    const float* __restrict__ bias,
    bf16_t* __restrict__ o0, bf16_t* __restrict__ o1, bf16_t* __restrict__ o2,
    int K) {
  extern __shared__ __align__(16) bf16_t smem[];
  // As: [2][256][64] at 0 ; Bs: [2][288][64] at 32768 (elems)
  constexpr int ASZ = 256 * 64;   // 16384 elems per A buffer
  constexpr int BSZ = 288 * 64;   // 18432 elems per B buffer
  bf16_t* Bbase = smem + 2 * ASZ;

  const int tid = threadIdx.x;
  const int w = tid >> 6, lane = tid & 63;   // w: 0..11
  const int wr = w / 6, wc = w % 6;          // 2M x 6N wave grid
  const int quad = lane >> 4, l16 = lane & 15;

  // XCD-aware decode: grid = 256 = 8 n-tiles x 32 m-tiles, 32 blocks/XCD.
  const int id = blockIdx.x;
  const int xcd = id & 7;
  const int lin = id >> 3;          // 0..31
  const int nt = lin & 7;           // n fastest
  const int mt = (xcd << 2) + (lin >> 3);

  // DMA mapping: lane -> row lane>>3 of an 8-row chunk, LDS slot lane&7;
  // fetch global chunk ((lane&7) - row)&7 so that slot = (chunk + row)&7.
  const int dr = lane >> 3;
  const int dc = (((lane & 7) - dr) & 7) << 3;  // element offset

  // Swizzle-corrected fragment read offsets (rows base+l16, base%16==0).
  const int so0 = ((quad + (l16 & 7)) & 7) << 3;  // ks=0
  const int so1 = so0 ^ 32;                       // ks=1 (chunk+4 == slot^4)

  f32x4 acc[8][3] = {};

  // 68 staging units per K-tile: u<32 -> A chunk u (8 rows), else B chunk u-32.
  auto stage = [&](int t, int s) {
    const size_t ko = (size_t)t * 64 + dc;
#pragma unroll
    for (int j = 0; j < 6; ++j) {
      const int u = w + j * 12;
      if (u < 32) {
        GLOAD_LDS16(A + (size_t)(mt * 256 + u * 8 + dr) * K + ko,
                    smem + s * ASZ + u * 8 * 64);
      } else if (u < 68) {
        const int v = u - 32;
        GLOAD_LDS16(BT + (size_t)(nt * 288 + v * 8 + dr) * K + ko,
                    Bbase + s * BSZ + v * 8 * 64);
      }
    }
  };

  auto compute = [&](int s) {
#pragma unroll
    for (int ks = 0; ks < 2; ++ks) {
      const int so = ks ? so1 : so0;
      bf16x8 bfrag[3], afrag[8];
#pragma unroll
      for (int ni = 0; ni < 3; ++ni)
        bfrag[ni] = *(const bf16x8*)(Bbase + s * BSZ +
                                     (wc * 48 + ni * 16 + l16) * 64 + so);
#pragma unroll
      for (int mi = 0; mi < 8; ++mi)
        afrag[mi] = *(const bf16x8*)(smem + s * ASZ +
                                     (wr * 128 + mi * 16 + l16) * 64 + so);
      __builtin_amdgcn_s_setprio(1);
#pragma unroll
      for (int mi = 0; mi < 8; ++mi)
#pragma unroll
        for (int ni = 0; ni < 3; ++ni)
          acc[mi][ni] = MFMA16(afrag[mi], bfrag[ni], acc[mi][ni]);
      __builtin_amdgcn_s_setprio(0);
    }
  };

  const int NIT = K / 64;  // 12
  stage(0, 0);
  __syncthreads();  // tile 0 landed (implicit vmcnt(0)), all waves synced
  for (int t = 0; t < NIT; ++t) {
    if (t + 1 < NIT) stage(t + 1, (t + 1) & 1);  // issue BEFORE compute
    compute(t & 1);
    if (t + 1 < NIT) __syncthreads();  // drains stage(t+1); WAR-safe for slot
  }

  // Epilogue. C/D layout: col = l16 (n), row = quad*4 + r (m).
  const int m_base = mt * 256 + wr * 128;
  const int n_base = nt * 288 + wc * 48;
#pragma unroll
  for (int ni = 0; ni < 3; ++ni) {
    const int n = n_base + ni * 16 + l16;
    const float bv = bias[n];
    const int which = n / 768;
    const int c = n - which * 768;
    const int h = c >> 6, d = c & 63;
#pragma unroll
    for (int mi = 0; mi < 8; ++mi) {
#pragma unroll
      for (int r = 0; r < 4; ++r) {
        const int m = m_base + mi * 16 + quad * 4 + r;
        const bf16_t bw = (bf16_t)(acc[mi][ni][r] + bv);
        const int b = m >> 10, t = m & 1023;
        const size_t bh = (size_t)(b * 12 + h);
        if (which == 0)
          o0[(bh * 1024 + t) * 64 + d] = bw;
        else if (which == 1)
          o1[(bh * 1024 + t) * 64 + d] = bw;
        else
          o2[(bh * 64 + d) * 1024 + t] = bw;
      }
    }
  }
}

// ---------------------------------------------------------------------------
// Proj GEMM (verified structure): of[M][N] = A*BT^T + bias, fp32 out.
// XCD-aware decode. nwg=384 -> each XCD owns 8 m-tiles x all 6 n-tiles.
// ---------------------------------------------------------------------------
__global__ __launch_bounds__(256) void gemm_proj(
    const bf16_t* __restrict__ A, const bf16_t* __restrict__ BT,
    const float* __restrict__ bias, float* __restrict__ of, int N, int K) {
  constexpr int BM = 128, BN = 128, BK = 32;
  __shared__ __align__(16) bf16_t As[2][BM][BK];
  __shared__ __align__(16) bf16_t Bs[2][BN][BK];

  const int tid = threadIdx.x;
  const int wave = tid >> 6, lane = tid & 63;
  const int wr = wave >> 1, wc = wave & 1;
  const int quad = lane >> 4, l16 = lane & 15;

  // XCD-aware decode: grid = 384 = 6 n-tiles x 64 m-tiles.
  const int id = blockIdx.x;
  const int xcd = id & 7;
  const int lin = id >> 3;     // 0..47
  const int nt = lin % 6;
  const int mt = xcd * 8 + lin / 6;

  const int rl = lane >> 2;
  const int cq = ((lane & 3) - (rl >> 1)) & 3;
  const int ac = cq << 3;
  const bf16_t* Ag0 = A + (size_t)(mt * BM + wave * 32 + rl) * K + ac;
  const bf16_t* Ag1 = Ag0 + (size_t)16 * K;
  const bf16_t* Bg0 = BT + (size_t)(nt * BN + wave * 32 + rl) * K + ac;
  const bf16_t* Bg1 = Bg0 + (size_t)16 * K;

  const int sw = ((quad + (l16 >> 1)) & 3) << 3;

  f32x4 acc[4][4] = {};

  auto stage = [&](int k0, int buf) {
    GLOAD_LDS16(Ag0 + k0, &As[buf][wave * 32][0]);
    GLOAD_LDS16(Ag1 + k0, &As[buf][wave * 32 + 16][0]);
    GLOAD_LDS16(Bg0 + k0, &Bs[buf][wave * 32][0]);
    GLOAD_LDS16(Bg1 + k0, &Bs[buf][wave * 32 + 16][0]);
  };
  auto compute = [&](int buf) {
    bf16x8 af[4], bfr[4];
#pragma unroll
    for (int mi = 0; mi < 4; ++mi)
      af[mi] = *(const bf16x8*)(&As[buf][wr * 64 + mi * 16 + l16][sw]);
#pragma unroll
    for (int ni = 0; ni < 4; ++ni)
      bfr[ni] = *(const bf16x8*)(&Bs[buf][wc * 64 + ni * 16 + l16][sw]);
#pragma unroll
    for (int mi = 0; mi < 4; ++mi)
#pragma unroll
      for (int ni = 0; ni < 4; ++ni)
        acc[mi][ni] = MFMA16(af[mi], bfr[ni], acc[mi][ni]);
  };

  const int NIT = K / BK;  // 24
  stage(0, 0);
  for (int k = 0; k + 2 < NIT; k += 2) {
    __syncthreads();
    stage((k + 1) * BK, 1);
    compute(0);
    __syncthreads();
    stage((k + 2) * BK, 0);
    compute(1);
  }
  __syncthreads();
  stage((NIT - 1) * BK, 1);
  compute(0);
  __syncthreads();
  compute(1);

  const int m_base = mt * BM + wr * 64;
  const int n_base = nt * BN + wc * 64;
#pragma unroll
  for (int ni = 0; ni < 4; ++ni) {
    const int n = n_base + ni * 16 + l16;
    const float bv = bias[n];
#pragma unroll
    for (int mi = 0; mi < 4; ++mi)
#pragma unroll
      for (int r = 0; r < 4; ++r) {
        const int m = m_base + mi * 16 + quad * 4 + r;
        of[(size_t)m * N + n] = acc[mi][ni][r] + bv;
      }
  }
}

// ---------------------------------------------------------------------------
// Causal flash attention, DMA-staged K/V, double-buffered, ONE barrier/tile.
// Q,K: [B*H][1024][64]; VT: [B*H][64][1024]; Y: [B][1024][768].
// XCD-aware decode: each XCD owns one batch b; the 8 pair-blocks sharing a
// head's K/V are co-located on one XCD's L2.
// ---------------------------------------------------------------------------
__global__ __launch_bounds__(256) void attn_fwd(
    const bf16_t* __restrict__ Q, const bf16_t* __restrict__ Kg,
    const bf16_t* __restrict__ VT, bf16_t* __restrict__ Y) {
  __shared__ __align__(16) bf16_t Ks[2][64][64];  // 16 KB
  __shared__ __align__(16) bf16_t Vs[2][64][64];  // 16 KB  (row = d)
  __shared__ __align__(16) bf16_t Ps[4][16][72];  // 9 KB, padded (VALU-written)

  const int tid = threadIdx.x;
  const int w = tid >> 6, lane = tid & 63;
  const int quad = lane >> 4, l16 = lane & 15;

  // XCD-aware decode: grid = 768 = 8 pairs x 12 h x 8 b.
  const int id = blockIdx.x;
  const int xcd = id & 7;
  const int lin = id >> 3;          // 0..95
  const int pair = lin & 7;
  const int h = lin >> 3;           // 0..11
  const int b = xcd;                // each XCD owns one batch
  const size_t bh = (size_t)(b * 12 + h);
  const bf16_t* Qbh = Q + bh * 65536;
  const bf16_t* Kbh = Kg + bh * 65536;
  const bf16_t* VTbh = VT + bh * 65536;

  // DMA fetch mapping: lane -> row lane>>3 (of an 8-row group), slot lane&7,
  // fetches global chunk (slot - row)&7 so that slot = (chunk + row)&7.
  const int drow = lane >> 3;
  const int dchunk = (((lane & 7) - drow) & 7) << 3;  // element offset

  // swizzle-corrected fragment read offsets (rows base+l16, base%16==0)
  const int so0 = ((quad + (l16 & 7)) & 7) << 3;
  const int so1 = so0 ^ 32;

  constexpr float SC = 0.18033688011112042f;  // log2(e) / sqrt(64)
  const bf16_t one_b = (bf16_t)1.0f;
  const bf16x8 ones = {one_b, one_b, one_b, one_b,
                       one_b, one_b, one_b, one_b};

  auto stageKV = [&](int kt, int bufi) {
#pragma unroll
    for (int j = 0; j < 2; ++j) {
      const int r = w * 16 + j * 8 + drow;
      GLOAD_LDS16(Kbh + (size_t)(kt * 64 + r) * 64 + dchunk,
                  &Ks[bufi][w * 16 + j * 8][0]);
      GLOAD_LDS16(VTbh + (size_t)r * 1024 + kt * 64 + dchunk,
                  &Vs[bufi][w * 16 + j * 8][0]);
    }
  };

  for (int phase = 0; phase < 2; ++phase) {
    const int qt = phase ? pair : (15 - pair);  // big tile first

    const int qrow = qt * 64 + w * 16 + l16;
    bf16x8 qf0 = *(const bf16x8*)(Qbh + (size_t)qrow * 64 + quad * 8);
    bf16x8 qf1 = *(const bf16x8*)(Qbh + (size_t)qrow * 64 + 32 + quad * 8);

    float m_r[4];
    f32x4 o[5] = {};  // o[0..3]: V columns; o[4]: row-sum (l)
#pragma unroll
    for (int r = 0; r < 4; ++r) m_r[r] = -INFINITY;

    __syncthreads();  // all waves done reading prev-phase LDS
    stageKV(0, 0);
    int buf = 0;
    for (int kt = 0; kt <= qt; ++kt) {
      __syncthreads();  // DMA(kt) landed; prior reads of buf^1 done
      if (kt < qt) stageKV(kt + 1, buf ^ 1);

      // S = Q * K^T
      f32x4 s[4];
#pragma unroll
      for (int ni = 0; ni < 4; ++ni) {
        bf16x8 kf0 = *(const bf16x8*)(&Ks[buf][ni * 16 + l16][so0]);
        bf16x8 kf1 = *(const bf16x8*)(&Ks[buf][ni * 16 + l16][so1]);
        f32x4 t = {};
        t = MFMA16(qf0, kf0, t);
        t = MFMA16(qf1, kf1, t);
        s[ni] = t;
      }
      if (kt == qt) {
#pragma unroll
        for (int ni = 0; ni < 4; ++ni)
#pragma unroll
          for (int r = 0; r < 4; ++r) {
            const int kp = ni * 16 + l16;
            const int qr = w * 16 + quad * 4 + r;
            s[ni][r] = (kp > qr) ? -INFINITY : s[ni][r] * SC;
          }
      } else {
#pragma unroll
        for (int ni = 0; ni < 4; ++ni)
#pragma unroll
          for (int r = 0; r < 4; ++r) s[ni][r] *= SC;
      }
      float alpha[4];
#pragma unroll
      for (int r = 0; r < 4; ++r) {
        float v = fmaxf(fmaxf(s[0][r], s[1][r]), fmaxf(s[2][r], s[3][r]));
        v = fmaxf(v, __shfl_xor(v, 1));
        v = fmaxf(v, __shfl_xor(v, 2));
        v = fmaxf(v, __shfl_xor(v, 4));
        v = fmaxf(v, __shfl_xor(v, 8));
        const float mn = fmaxf(m_r[r], v);
        alpha[r] = exp2f(m_r[r] - mn);
        m_r[r] = mn;
      }
      // P -> Ps (per-wave region; intra-wave dependency only, no barrier)
#pragma unroll
      for (int ni = 0; ni < 4; ++ni)
#pragma unroll
        for (int r = 0; r < 4; ++r)
          Ps[w][quad * 4 + r][ni * 16 + l16] =
              (bf16_t)exp2f(s[ni][r] - m_r[r]);
#pragma unroll
      for (int nd = 0; nd < 5; ++nd)
#pragma unroll
        for (int r = 0; r < 4; ++r) o[nd][r] *= alpha[r];

      bf16x8 pf0 = *(const bf16x8*)(&Ps[w][l16][quad * 8]);
      bf16x8 pf1 = *(const bf16x8*)(&Ps[w][l16][32 + quad * 8]);
#pragma unroll
      for (int nd = 0; nd < 4; ++nd) {
        bf16x8 vf0 = *(const bf16x8*)(&Vs[buf][nd * 16 + l16][so0]);
        bf16x8 vf1 = *(const bf16x8*)(&Vs[buf][nd * 16 + l16][so1]);
        o[nd] = MFMA16(pf0, vf0, o[nd]);
        o[nd] = MFMA16(pf1, vf1, o[nd]);
      }
      o[4] = MFMA16(pf0, ones, o[4]);
      o[4] = MFMA16(pf1, ones, o[4]);
      buf ^= 1;
    }

#pragma unroll
    for (int r = 0; r < 4; ++r) {
      const float inv = 1.0f / o[4][r];
      const int t = qt * 64 + w * 16 + quad * 4 + r;
      bf16_t* yrow = Y + ((size_t)b * 1024 + t) * 768 + h * 64;
#pragma unroll
      for (int nd = 0; nd < 4; ++nd)
        yrow[nd * 16 + l16] = (bf16_t)(o[nd][r] * inv);
    }
  }
}

// ---------------------------------------------------------------------------
extern "C" void kernel_launch(void* const* d_in, const int* in_sizes, int n_in,
                              void* d_out, int out_size, void* d_ws,
                              size_t ws_size, hipStream_t stream) {
  const float* x      = (const float*)d_in[0];
  const float* W_attn = (const float*)d_in[1];
  const float* b_attn = (const float*)d_in[2];
  const float* W_proj = (const float*)d_in[3];
  const float* b_proj = (const float*)d_in[4];
  float* out = (float*)d_out;   // fp32 output per reference dtype

  const size_t HEADS = 96;  // B*H = 8*12
  bf16_t* wta = (bf16_t*)d_ws;                  // [2304][768]
  bf16_t* wtp = wta + (size_t)2304 * 768;       // [768][768]
  bf16_t* qw  = wtp + (size_t)768 * 768;        // [96][1024][64]
  bf16_t* kw  = qw + HEADS * 1024 * 64;         // [96][1024][64]
  bf16_t* vtw = kw + HEADS * 1024 * 64;         // [96][64][1024]
  bf16_t* yw  = vtw + HEADS * 1024 * 64;        // [8192][768]
  bf16_t* xb  = yw + (size_t)8192 * 768;        // [8192][768] bf16 x

  f32_to_bf16<<<dim3(8192 * 768 / (256 * 8)), 256, 0, stream>>>(x, xb);
  transpose_f32_to_bf16<<<dim3(2304 / 32, 768 / 32), 256, 0, stream>>>(
      W_attn, wta, 768, 2304);
  transpose_f32_to_bf16<<<dim3(768 / 32, 768 / 32), 256, 0, stream>>>(
      W_proj, wtp, 768, 768);
  // Dynamic LDS: 2 bufs x (256 + 288) rows x 64 bf16 = 136 KB.
  const size_t qkv_lds = (size_t)(2 * (256 + 288) * 64) * sizeof(bf16_t);
  gemm_qkv<<<dim3(256), 768, qkv_lds, stream>>>(
      xb, wta, b_attn, qw, kw, vtw, 768);
  attn_fwd<<<dim3(768), 256, 0, stream>>>(qw, kw, vtw, yw);
  gemm_proj<<<dim3(384), 256, 0, stream>>>(
      yw, wtp, b_proj, out, 768, 768);
}